// Round 1
// baseline (917.194 us; speedup 1.0000x reference)
//
#include <hip/hip_runtime.h>
#include <stdint.h>

#define B_DIM 16384
#define V_DIM 1024
#define H_DIM 256
#define K_STEPS 8

typedef short bf16x8 __attribute__((ext_vector_type(8)));
typedef float f32x4 __attribute__((ext_vector_type(4)));

// ---------------- Threefry-2x32-20, bit-exact JAX replica ----------------
__host__ __device__ inline uint32_t rotl32(uint32_t v, int r) {
#if defined(__HIP_DEVICE_COMPILE__)
    return __builtin_amdgcn_alignbit(v, v, (uint32_t)(32 - r));
#else
    return (v << r) | (v >> (32 - r));
#endif
}

__host__ __device__ inline void threefry2x32(uint32_t k0, uint32_t k1,
                                             uint32_t x0, uint32_t x1,
                                             uint32_t* o0, uint32_t* o1) {
    uint32_t k2 = k0 ^ k1 ^ 0x1BD11BDAu;
    x0 += k0; x1 += k1;
#define TF_RND(r) { x0 += x1; x1 = rotl32(x1, (r)); x1 ^= x0; }
    TF_RND(13) TF_RND(15) TF_RND(26) TF_RND(6)
    x0 += k1; x1 += k2 + 1u;
    TF_RND(17) TF_RND(29) TF_RND(16) TF_RND(24)
    x0 += k2; x1 += k0 + 2u;
    TF_RND(13) TF_RND(15) TF_RND(26) TF_RND(6)
    x0 += k0; x1 += k1 + 3u;
    TF_RND(17) TF_RND(29) TF_RND(16) TF_RND(24)
    x0 += k1; x1 += k2 + 4u;
    TF_RND(13) TF_RND(15) TF_RND(26) TF_RND(6)
    x0 += k2; x1 += k0 + 5u;
#undef TF_RND
    *o0 = x0; *o1 = x1;
}

// Partitionable-threefry uniform (bits = o0 ^ o1 of counter (0, e)).
__device__ inline float tf_uniform(uint32_t key0, uint32_t key1, uint32_t e) {
    uint32_t o0, o1;
    threefry2x32(key0, key1, 0u, e, &o0, &o1);
    uint32_t bits = o0 ^ o1;
    return __uint_as_float((bits >> 9) | 0x3f800000u) - 1.0f;
}

__device__ inline uint16_t bf16_rn(float f) {
    uint32_t u = __float_as_uint(f);
    uint32_t r = u + 0x7FFFu + ((u >> 16) & 1u);
    return (uint16_t)(r >> 16);
}
__device__ inline float bf16_to_f32(uint16_t h) {
    return __uint_as_float(((uint32_t)h) << 16);
}

__device__ inline void gload_lds16(const void* g, void* l) {
    __builtin_amdgcn_global_load_lds((const __attribute__((address_space(1))) uint32_t*)g,
                                     (__attribute__((address_space(3))) uint32_t*)l, 16, 0, 0);
}

struct KeyPack { uint32_t hk0[8], hk1[8], vk0[8], vk1[8]; };

// ---------------- Fused Gibbs chain: 9x (h-GEMM) + 8x (h-sample + v-sample) ----------
// One block per 32-row stripe (rows are independent through the chain).
// Phase A: pre_h[32x256] = v[32x1024] @ W^T (hi+lo split) + hb   (MFMA, LDS-staged)
// Phase B: sample h from acc frags -> h bits into LDS (reuses BhS[0]); step0 also ph0.
// Phase C: sparse v-pre from active h rows of W (fp32, L2-hot), sample v -> global.
// step==K_STEPS runs phase A only and writes phk = sigmoid(pre) (bf16).
// 512 threads (8 waves, 2x4 wave grid over 32x256), 68 KB LDS -> 2 blocks/CU so one
// block's threefry VALU overlaps the other block's MFMA.
__global__ __launch_bounds__(512, 4) void gibbs_fused(
    const ushort* __restrict__ batch_bf,
    const ushort* __restrict__ Whi, const ushort* __restrict__ Wlo,
    const float* __restrict__ Wf, const float* __restrict__ vb,
    const float* __restrict__ hb, ushort* __restrict__ v_cur,
    ushort* __restrict__ ph0b, ushort* __restrict__ phkb, KeyPack kp) {
    __shared__ __align__(16) ushort As[2][32 * 32];
    __shared__ __align__(16) ushort BhS[2][256 * 32];
    __shared__ __align__(16) ushort BlS[2][256 * 32];

    const int tid = threadIdx.x;
    const int lane = tid & 63;
    const int w = tid >> 6;            // 0..7
    const int m0 = blockIdx.x * 32;

    const int wm = (w & 1) * 16;       // M sub-tile (16 rows)
    const int wn = (w >> 1) * 64;      // N sub-tile (64 cols)
    const int q = lane >> 4;
    const int l15 = lane & 15;
    const int srow = lane >> 2;
    const int scol = (lane & 3) * 8;

    ushort* h_lds = &BhS[0][0];        // [32][256] bits, valid after phase A

    for (int step = 0; step <= K_STEPS; ++step) {
        const ushort* Asrc = (step == 0) ? batch_bf : v_cur;
        f32x4 acc[4] = {};

        for (int k0 = 0; k0 < V_DIM; k0 += 64) {
            if (w < 4) {
                const int s = w & 1, rh = w >> 1;
                gload_lds16(&Asrc[(size_t)(m0 + rh * 16 + srow) * V_DIM + k0 + s * 32 + scol],
                            &As[s][rh * 512]);
            }
#pragma unroll
            for (int c = 0; c < 4; ++c) {
                const int cc = w + 8 * c;          // 0..31, each (s,rb) exactly once
                const int s = cc & 1, rb = cc >> 1;
                const size_t off = (size_t)(rb * 16 + srow) * V_DIM + k0 + s * 32 + scol;
                gload_lds16(&Whi[off], &BhS[s][rb * 512]);
                gload_lds16(&Wlo[off], &BlS[s][rb * 512]);
            }
            __syncthreads();
#pragma unroll
            for (int s = 0; s < 2; ++s) {
                bf16x8 af = *(const bf16x8*)&As[s][(wm + l15) * 32 + q * 8];
#pragma unroll
                for (int j = 0; j < 4; ++j) {
                    bf16x8 bh = *(const bf16x8*)&BhS[s][(wn + j * 16 + l15) * 32 + q * 8];
                    bf16x8 bl = *(const bf16x8*)&BlS[s][(wn + j * 16 + l15) * 32 + q * 8];
                    acc[j] = __builtin_amdgcn_mfma_f32_16x16x32_bf16(af, bh, acc[j], 0, 0, 0);
                    acc[j] = __builtin_amdgcn_mfma_f32_16x16x32_bf16(af, bl, acc[j], 0, 0, 0);
                }
            }
            __syncthreads();
        }

        if (step == K_STEPS) {
            // final phk = sigmoid(pre_k), precise divide, bf16
#pragma unroll
            for (int j = 0; j < 4; ++j) {
                const int col = wn + j * 16 + l15;
                const float hbv = hb[col];
#pragma unroll
                for (int r = 0; r < 4; ++r) {
                    const int row = m0 + wm + q * 4 + r;
                    float val = acc[j][r] + hbv;
                    phkb[(size_t)row * H_DIM + col] = bf16_rn(1.0f / (1.0f + expf(-val)));
                }
            }
            break;  // uniform across block
        }

        // ---- phase B: sample h into LDS (and ph0 at step 0) ----
        const uint32_t kh0 = kp.hk0[step], kh1 = kp.hk1[step];
#pragma unroll
        for (int j = 0; j < 4; ++j) {
            const int col = wn + j * 16 + l15;
            const float hbv = hb[col];
#pragma unroll
            for (int r = 0; r < 4; ++r) {
                const int rowl = wm + q * 4 + r;
                const int row = m0 + rowl;
                float val = acc[j][r] + hbv;
                float E = expf(-val);
                float u = tf_uniform(kh0, kh1, (uint32_t)row * (uint32_t)H_DIM + (uint32_t)col);
                // u < 1/(1+E)  <=>  fma(u,E,u) < 1 ; proven flip-free in prior session
                h_lds[rowl * H_DIM + col] = (fmaf(u, E, u) < 1.0f) ? (ushort)0x3F80 : (ushort)0;
                if (step == 0) {
                    ph0b[(size_t)row * H_DIM + col] = bf16_rn(1.0f / (1.0f + E));
                }
            }
        }
        __syncthreads();

        // ---- phase C: sparse v-side sampler (round-8 proven body) ----
        const uint32_t kv0 = kp.vk0[step], kv1 = kp.vk1[step];
        float vbr[16];
#pragma unroll
        for (int t = 0; t < 16; ++t) vbr[t] = vb[lane + 64 * t];
#pragma unroll
        for (int rr = 0; rr < 4; ++rr) {
            const int bl_ = w * 4 + rr;     // local row 0..31
            const int b = m0 + bl_;
            ushort4 hv = ((const ushort4*)(h_lds + bl_ * H_DIM))[lane];
            unsigned long long masks[4];
            masks[0] = __ballot(hv.x != 0);
            masks[1] = __ballot(hv.y != 0);
            masks[2] = __ballot(hv.z != 0);
            masks[3] = __ballot(hv.w != 0);

            float acc2[16];
#pragma unroll
            for (int t = 0; t < 16; ++t) acc2[t] = 0.0f;

#pragma unroll
            for (int s = 0; s < 4; ++s) {
                unsigned long long m = masks[s];
                while (m) {  // wave-uniform loop, no divergence
                    int l = __ffsll(m) - 1;
                    m &= m - 1;
                    int jj = l * 4 + s;
                    const float* wrow = Wf + (size_t)jj * V_DIM + lane;
#pragma unroll
                    for (int t = 0; t < 16; ++t) acc2[t] += wrow[64 * t];
                }
            }

            const uint32_t ebase = (uint32_t)b * (uint32_t)V_DIM + (uint32_t)lane;
            ushort* orow = v_cur + (size_t)b * V_DIM + lane;
#pragma unroll
            for (int t = 0; t < 16; ++t) {
                float pre = acc2[t] + vbr[t];
                float E = expf(-pre);
                float u = tf_uniform(kv0, kv1, ebase + 64u * (uint32_t)t);
                orow[64 * t] = (fmaf(u, E, u) < 1.0f) ? (ushort)0x3F80 : (ushort)0;
            }
        }
        __syncthreads();  // v_cur stores drained (vmcnt0 before barrier) before re-staging
    }
}

// ---------------- LDS MFMA NT-GEMM accumulate (gw) ----------------
__global__ __launch_bounds__(256, 4) void mfma_gemm_acc(
    const ushort* __restrict__ A, const ushort* __restrict__ Bt,
    float* __restrict__ out, int N, int K, int k_slice) {
    __shared__ __align__(16) ushort As[64 * 32];
    __shared__ __align__(16) ushort Bs[64 * 32];

    const int tid = threadIdx.x;
    const int lane = tid & 63;
    const int w = tid >> 6;
    const int m0 = blockIdx.x * 64;
    const int n0 = blockIdx.y * 64;
    const int kbase = blockIdx.z * k_slice;

    f32x4 acc[2][2] = {};

    const int wm = (w & 1) * 32;
    const int wn = (w >> 1) * 32;
    const int q = lane >> 4;
    const int l15 = lane & 15;
    const int srow = lane >> 2;
    const int scol = (lane & 3) * 8;

    const size_t arow = (size_t)(m0 + w * 16 + srow) * K;
    const size_t brow = (size_t)(n0 + w * 16 + srow) * K;

    for (int kt = 0; kt < k_slice; kt += 32) {
        const int k0 = kbase + kt;
        gload_lds16(&A[arow + k0 + scol], &As[w * 512]);
        gload_lds16(&Bt[brow + k0 + scol], &Bs[w * 512]);
        __syncthreads();
        bf16x8 af[2], bf[2];
#pragma unroll
        for (int i = 0; i < 2; ++i) {
            af[i] = *(const bf16x8*)&As[(wm + i * 16 + l15) * 32 + q * 8];
            bf[i] = *(const bf16x8*)&Bs[(wn + i * 16 + l15) * 32 + q * 8];
        }
#pragma unroll
        for (int i = 0; i < 2; ++i)
#pragma unroll
            for (int j = 0; j < 2; ++j)
                acc[i][j] = __builtin_amdgcn_mfma_f32_16x16x32_bf16(af[i], bf[j], acc[i][j], 0, 0, 0);
        __syncthreads();
    }

    const int orow = q * 4;
#pragma unroll
    for (int i = 0; i < 2; ++i)
#pragma unroll
        for (int j = 0; j < 2; ++j) {
            int col = n0 + wn + j * 16 + l15;
#pragma unroll
            for (int r = 0; r < 4; ++r) {
                int row = m0 + wm + i * 16 + orow + r;
                atomicAdd(&out[(size_t)row * N + col], acc[i][j][r]);
            }
        }
}

// ---------------- W split into bf16 hi/lo ----------------
__global__ void wsplit_kernel(const float* __restrict__ W, ushort* __restrict__ whi,
                              ushort* __restrict__ wlo) {
    int idx = blockIdx.x * 256 + threadIdx.x;
    float w = W[idx];
    ushort hi = bf16_rn(w);
    float fhi = bf16_to_f32(hi);
    ushort lo = bf16_rn(w - fhi);
    whi[idx] = hi; wlo[idx] = lo;
}

__global__ void tobf16_kernel(const float* __restrict__ src, ushort* __restrict__ dst) {
    int idx = blockIdx.x * 256 + threadIdx.x;
    float4 f = ((const float4*)src)[idx];
    ushort4 o;
    o.x = bf16_rn(f.x); o.y = bf16_rn(f.y); o.z = bf16_rn(f.z); o.w = bf16_rn(f.w);
    ((ushort4*)dst)[idx] = o;
}

// ---------------- log-norm ----------------
__global__ __launch_bounds__(256) void lognorm_kernel(
    const ushort* __restrict__ phk, const ushort* __restrict__ vk,
    const float* __restrict__ vb, float* __restrict__ inv) {
    int b = blockIdx.x;
    int tid = threadIdx.x;
    float p = bf16_to_f32(phk[(size_t)b * H_DIM + tid]);
    float s = -log1pf(-p);
    for (int j = tid; j < V_DIM; j += 256)
        s += bf16_to_f32(vk[(size_t)b * V_DIM + j]) * vb[j];
    for (int off = 32; off > 0; off >>= 1) s += __shfl_down(s, off, 64);
    __shared__ float wsum[4];
    int lane = tid & 63, wid = tid >> 6;
    if (lane == 0) wsum[wid] = s;
    __syncthreads();
    if (tid == 0) {
        float t = wsum[0] + wsum[1] + wsum[2] + wsum[3];
        inv[b] = expf(-t) * (1.0f / 16384.0f);
    }
}

// ---------------- transposes for gw GEMM ----------------
__global__ void build_At(const ushort* __restrict__ P, const float* __restrict__ inv,
                         float sgn, ushort* __restrict__ At) {
    __shared__ float T[64][65];
    int c = threadIdx.x & 63;
    int rb = threadIdx.x >> 6;
    int b0 = blockIdx.x * 64;
    int h0 = blockIdx.y * 64;
    for (int r = rb; r < 64; r += 4) {
        int b = b0 + r;
        T[c][r] = sgn * inv[b] * bf16_to_f32(P[(size_t)b * H_DIM + h0 + c]);
    }
    __syncthreads();
    for (int r = rb; r < 64; r += 4)
        At[(size_t)(h0 + r) * B_DIM + b0 + c] = bf16_rn(T[r][c]);
}

__global__ void build_Bt(const ushort* __restrict__ Sb, const float* __restrict__ Sf,
                         int use_f32, ushort* __restrict__ Bt) {
    __shared__ ushort T[64][65];
    int c = threadIdx.x & 63;
    int rb = threadIdx.x >> 6;
    int b0 = blockIdx.x * 64;
    int v0 = blockIdx.y * 64;
    for (int r = rb; r < 64; r += 4) {
        int b = b0 + r;
        T[c][r] = use_f32 ? bf16_rn(Sf[(size_t)b * V_DIM + v0 + c])
                          : Sb[(size_t)b * V_DIM + v0 + c];
    }
    __syncthreads();
    for (int r = rb; r < 64; r += 4)
        Bt[(size_t)(v0 + r) * B_DIM + b0 + c] = T[r][c];
}

// ---------------- g_vb / g_hb ----------------
__global__ void gvb_kernel(const ushort* __restrict__ vk, const ushort* __restrict__ vbat,
                           const float* __restrict__ inv, float* __restrict__ gvb) {
    int col = blockIdx.x * 256 + threadIdx.x;
    int b0 = blockIdx.y * 512;
    float acc = 0.0f;
    for (int r = 0; r < 512; ++r) {
        int b = b0 + r;
        acc += inv[b] * (bf16_to_f32(vk[(size_t)b * V_DIM + col]) -
                         bf16_to_f32(vbat[(size_t)b * V_DIM + col]));
    }
    atomicAdd(&gvb[col], acc);
}

__global__ void ghb_kernel(const ushort* __restrict__ phk, const ushort* __restrict__ ph0,
                           const float* __restrict__ inv, float* __restrict__ ghb) {
    int col = threadIdx.x;
    int b0 = blockIdx.x * 256;
    float acc = 0.0f;
    for (int r = 0; r < 256; ++r) {
        int b = b0 + r;
        acc += inv[b] * (bf16_to_f32(phk[(size_t)b * H_DIM + col]) -
                         bf16_to_f32(ph0[(size_t)b * H_DIM + col]));
    }
    atomicAdd(&ghb[col], acc);
}

extern "C" void kernel_launch(void* const* d_in, const int* in_sizes, int n_in,
                              void* d_out, int out_size, void* d_ws, size_t ws_size,
                              hipStream_t stream) {
    const float* batch = (const float*)d_in[0];
    const float* W = (const float*)d_in[1];
    const float* vb = (const float*)d_in[2];
    const float* hb = (const float*)d_in[3];

    char* base = (char*)d_ws;
    ushort* w_hi  = (ushort*)(base + 0);          // 512 KB
    ushort* w_lo  = (ushort*)(base + 524288);
    ushort* v_cur = (ushort*)(base + 2097152);    // 32 MB
    float*  inv   = (float*)(base + 35651584);    // 64 KB
    ushort* At    = (ushort*)(base + 35717120);   // 8 MB
    ushort* batch_bf = (ushort*)(base + 44105728); // 32 MB (aliased: Bt after last use)
    ushort* Bt    = batch_bf;
    ushort* ph0b  = (ushort*)(base + 77660160);   // 8 MB
    ushort* phkb  = (ushort*)(base + 86048768);   // 8 MB -> total 94437376 B

    float* gw  = (float*)d_out;
    float* gvb = gw + (size_t)H_DIM * V_DIM;
    float* ghb = gvb + V_DIM;

    hipMemsetAsync(d_out, 0, (size_t)out_size * sizeof(float), stream);

    // Partitionable threefry split of key(42): subkey[n] = threefry((0,42),(0,n)).
    KeyPack kp;
    for (int i = 0; i < K_STEPS; ++i) {
        threefry2x32(0u, 42u, 0u, (uint32_t)(2 * i),     &kp.hk0[i], &kp.hk1[i]);
        threefry2x32(0u, 42u, 0u, (uint32_t)(2 * i + 1), &kp.vk0[i], &kp.vk1[i]);
    }

    wsplit_kernel<<<dim3(1024), dim3(256), 0, stream>>>(W, w_hi, w_lo);
    tobf16_kernel<<<dim3(B_DIM * V_DIM / 4 / 256), dim3(256), 0, stream>>>(batch, batch_bf);

    // Entire k=8 Gibbs chain + final phk pass, fused (rows are independent).
    gibbs_fused<<<dim3(B_DIM / 32), dim3(512), 0, stream>>>(
        batch_bf, w_hi, w_lo, W, vb, hb, v_cur, ph0b, phkb, kp);

    lognorm_kernel<<<dim3(B_DIM), dim3(256), 0, stream>>>(phkb, v_cur, vb, inv);
    ghb_kernel<<<dim3(B_DIM / 256), dim3(256), 0, stream>>>(phkb, ph0b, inv, ghb);
    gvb_kernel<<<dim3(V_DIM / 256, B_DIM / 512), dim3(256), 0, stream>>>(v_cur, batch_bf, inv, gvb);

    // g_W positive phase
    build_At<<<dim3(B_DIM / 64, H_DIM / 64), dim3(256), 0, stream>>>(phkb, inv, 1.0f, At);
    build_Bt<<<dim3(B_DIM / 64, V_DIM / 64), dim3(256), 0, stream>>>(v_cur, nullptr, 0, Bt);
    mfma_gemm_acc<<<dim3(H_DIM / 64, V_DIM / 64, 16), dim3(256), 0, stream>>>(
        At, Bt, gw, V_DIM, B_DIM, 1024);
    // g_W negative phase
    build_At<<<dim3(B_DIM / 64, H_DIM / 64), dim3(256), 0, stream>>>(ph0b, inv, -1.0f, At);
    build_Bt<<<dim3(B_DIM / 64, V_DIM / 64), dim3(256), 0, stream>>>(nullptr, batch, 1, Bt);
    mfma_gemm_acc<<<dim3(H_DIM / 64, V_DIM / 64, 16), dim3(256), 0, stream>>>(
        At, Bt, gw, V_DIM, B_DIM, 1024);
}